// Round 18
// baseline (101.406 us; speedup 1.0000x reference)
//
#include <hip/hip_runtime.h>
#include <hip/hip_bf16.h>

#define B_ 8
#define T_ 8192
#define HID_ 256
#define C_ 5
#define K_ 16
#define NC_ 64    // chunks per batch
#define NTILE 32  // 256-position tiles per batch (cumsum pipeline)
#define GSPAN 144 // 16 pre-window + LMAX(128)
#define GW 148    // padded LDS row stride (floats); 148*4 % 16 == 0
#define GIOFF (5 * GW)
#define NFW 31    // fwd-chain matrices k=0..30 (stored TRANSPOSED); bwd: R(63), M62..M31

__device__ __forceinline__ float gelu_tanh(float x) {
    float u = 0.7978845608028654f * (x + 0.044715f * x * x * x);
    float e = __expf(2.0f * u);
    float th = 1.0f - 2.0f / (e + 1.0f);
    return 0.5f * x * (1.0f + th);
}

__device__ __forceinline__ float bf16lo(unsigned int u) {
    return __uint_as_float(u << 16);
}
__device__ __forceinline__ float bf16hi(unsigned int u) {
    return __uint_as_float(u & 0xffff0000u);
}
// DPP row shift (pure VALU): row_shr:N (0x110|N) = dst n <- src n-N (lower);
// row_shl:N (0x100|N) = dst n <- src n+N (higher). bound_ctrl=true -> 0 OOB.
template <int CTRL>
__device__ __forceinline__ float dppf(float x) {
    return __uint_as_float((unsigned int)__builtin_amdgcn_mov_dpp(
        (int)__float_as_uint(x), CTRL, 0xF, 0xF, true));
}

// ---------------- Kernel A: encoder (hidden split) -> emitA/emitB + per-tile class sums ----------------
__global__ __launch_bounds__(256) void encoder_kernel(
    const float* __restrict__ seq, const float* __restrict__ W_enc,
    const float* __restrict__ b_enc, const float* __restrict__ W_proj,
    const float* __restrict__ b_proj, float* __restrict__ emitA,
    float* __restrict__ emitB, float* __restrict__ PA)
{
    __shared__ float4 we[128];
    __shared__ float  be[128];
    __shared__ float  wp[128 * C_];
    __shared__ float  prd[4][C_];
    int tid = threadIdx.x;
    int half = blockIdx.x >> 8;
    int blk  = blockIdx.x & 255;
    int h0 = half * 128;
    if (tid < 128) {
        int h = h0 + tid;
        we[tid] = make_float4(W_enc[0*HID_+h], W_enc[1*HID_+h], W_enc[2*HID_+h], W_enc[3*HID_+h]);
        be[tid] = b_enc[h];
    }
    for (int i = tid; i < 128 * C_; i += 256) wp[i] = W_proj[h0 * C_ + i];
    __syncthreads();
    int b = blk >> 5;
    int tile = blk & 31;
    int t = tile * 256 + tid;
    float4 s = reinterpret_cast<const float4*>(seq)[(size_t)b * T_ + t];
    float a0, a1, a2, a3, a4;
    if (half == 0) { a0 = b_proj[0]; a1 = b_proj[1]; a2 = b_proj[2]; a3 = b_proj[3]; a4 = b_proj[4]; }
    else           { a0 = a1 = a2 = a3 = a4 = 0.0f; }
    #pragma unroll 8
    for (int h = 0; h < 128; ++h) {
        float4 w = we[h];
        float pre = be[h] + s.x*w.x + s.y*w.y + s.z*w.z + s.w*w.w;
        float hd = gelu_tanh(pre);
        a0 = fmaf(hd, wp[h*C_+0], a0);
        a1 = fmaf(hd, wp[h*C_+1], a1);
        a2 = fmaf(hd, wp[h*C_+2], a2);
        a3 = fmaf(hd, wp[h*C_+3], a3);
        a4 = fmaf(hd, wp[h*C_+4], a4);
    }
    float* em = half ? emitB : emitA;
    size_t base = (size_t)b * C_ * T_ + t;
    em[base + 0*T_] = a0;
    em[base + 1*T_] = a1;
    em[base + 2*T_] = a2;
    em[base + 3*T_] = a3;
    em[base + 4*T_] = a4;
    float s0 = a0, s1 = a1, s2 = a2, s3 = a3, s4 = a4;
    #pragma unroll
    for (int off = 1; off < 64; off <<= 1) {
        s0 += __shfl_xor(s0, off, 64);
        s1 += __shfl_xor(s1, off, 64);
        s2 += __shfl_xor(s2, off, 64);
        s3 += __shfl_xor(s3, off, 64);
        s4 += __shfl_xor(s4, off, 64);
    }
    int lane = tid & 63, wv = tid >> 6;
    if (lane == 0) { prd[wv][0]=s0; prd[wv][1]=s1; prd[wv][2]=s2; prd[wv][3]=s3; prd[wv][4]=s4; }
    __syncthreads();
    if (tid < C_) {
        float t4 = (prd[0][tid] + prd[1][tid]) + (prd[2][tid] + prd[3][tid]);
        PA[((half * B_ + b) * NTILE + tile) * C_ + tid] = t4;
    }
}

// ---------------- Kernel B: cum writer (one block per (b,c,tile)) ----------------
__global__ __launch_bounds__(64) void cumwrite_kernel(
    const float* __restrict__ emitA, const float* __restrict__ emitB,
    const float* __restrict__ PA, float* __restrict__ cum)
{
    int bx = blockIdx.x;
    int tile = bx & (NTILE - 1);
    int bc = bx >> 5;
    int b = bc / C_, c = bc - b * C_;
    int lane = threadIdx.x;
    float v = 0.0f;
    if (lane < NTILE && lane < tile)
        v = PA[((0 * B_ + b) * NTILE + lane) * C_ + c]
          + PA[((1 * B_ + b) * NTILE + lane) * C_ + c];
    #pragma unroll
    for (int o = 32; o; o >>= 1) v += __shfl_xor(v, o, 64);
    const float* eA = emitA + ((size_t)b * C_ + c) * T_;
    const float* eB = emitB + ((size_t)b * C_ + c) * T_;
    float* cb = cum + (size_t)b * (T_ + 1) * C_;
    if (tile == 0 && lane == 0) cb[c] = 0.0f;
    float carry = v;
    #pragma unroll
    for (int i = 0; i < 4; ++i) {
        int idx = tile * 256 + i * 64 + lane;
        float e = eA[idx] + eB[idx];
        float si = e;
        #pragma unroll
        for (int o = 1; o < 64; o <<= 1) {
            float n = __shfl_up(si, o, 64);
            if (lane >= o) si += n;
        }
        cb[(size_t)(idx + 1) * C_ + c] = carry + si;
        carry += __shfl(si, 63, 64);
    }
}

// ---------------- Kernel C: per-chunk 80x80 transfer matrices (DPP + prefetch) ----------------
#define DOT16(PP, OUT)                                                        \
    {                                                                         \
        float q0, q1, q2, q3;                                                 \
        q0 = W[0] * ed[(0 + (PP)) & 15];                                      \
        q1 = W[1] * ed[(1 + (PP)) & 15];                                      \
        q2 = W[2] * ed[(2 + (PP)) & 15];                                      \
        q3 = W[3] * ed[(3 + (PP)) & 15];                                      \
        q0 = fmaf(W[4],  ed[(4  + (PP)) & 15], q0);                           \
        q1 = fmaf(W[5],  ed[(5  + (PP)) & 15], q1);                           \
        q2 = fmaf(W[6],  ed[(6  + (PP)) & 15], q2);                           \
        q3 = fmaf(W[7],  ed[(7  + (PP)) & 15], q3);                           \
        q0 = fmaf(W[8],  ed[(8  + (PP)) & 15], q0);                           \
        q1 = fmaf(W[9],  ed[(9  + (PP)) & 15], q1);                           \
        q2 = fmaf(W[10], ed[(10 + (PP)) & 15], q2);                           \
        q3 = fmaf(W[11], ed[(11 + (PP)) & 15], q3);                           \
        q0 = fmaf(W[12], ed[(12 + (PP)) & 15], q0);                           \
        q1 = fmaf(W[13], ed[(13 + (PP)) & 15], q1);                           \
        q2 = fmaf(W[14], ed[(14 + (PP)) & 15], q2);                           \
        q3 = fmaf(W[15], ed[(15 + (PP)) & 15], q3);                           \
        OUT = (q0 + q1) + (q2 + q3);                                          \
    }

#define CSTEP(PP, GV, GIV, CAP)                                               \
    {                                                                         \
        P *= (GV); iP *= (GIV);                                               \
        float dtv;                                                            \
        DOT16(PP, dtv);                                                       \
        acur = P * dtv;                                                       \
        float r3  = dppf<0x113>(acur);  /* class c-1 */                       \
        float r6  = dppf<0x116>(acur);  /* class c-2 */                       \
        float r9  = dppf<0x119>(acur);  /* class c-3 */                       \
        float r12 = dppf<0x11C>(acur);  /* class c-4 */                       \
        float l3  = dppf<0x103>(acur);  /* class c+1 */                       \
        float l6  = dppf<0x106>(acur);  /* class c+2 */                       \
        float l9  = dppf<0x109>(acur);  /* class c+3 */                       \
        float l12 = dppf<0x10C>(acur);  /* class c+4 */                       \
        if (CAP) {                                                            \
            A0v = fmaf(a0w0, acur, fmaf(a0w1, r3, fmaf(a0w2, r6,              \
                  fmaf(a0w3, r9, a0w4 * r12))));                              \
        }                                                                     \
        float s01 = fmaf(wSelf, acur, wL1 * r3);                              \
        float s23 = fmaf(wL2, r6, wL3 * r9);                                  \
        float s45 = fmaf(wL4, r12, wR1 * l3);                                 \
        float s67 = fmaf(wR2, l6, wR3 * l9);                                  \
        float Sn = ((s01 + s23) + (s45 + s67)) + wR4 * l12;                   \
        W[15 - (PP)] = Sn * iP;                                               \
    }

#define CRENORM()                                                             \
    {                                                                         \
        bool ok = (A0v > 1e-30f);                                             \
        float rr = ok ? __builtin_amdgcn_rcpf(A0v) : 1.0f;                    \
        float lz = ok ? __logf(A0v) : 0.0f;                                   \
        float f = P * rr;                                                     \
        _Pragma("unroll") for (int q = 0; q < 16; ++q) W[q] *= f;             \
        P = 1.0f; iP = 1.0f; z += lz;                                         \
    }

// prefetched-window QBLK: consume vgc/vgic, prefetch next window at NX
#define QBLKP(Q, NX)                                                          \
    {                                                                         \
        float4 nvg  = *reinterpret_cast<const float4*>(gpg + (NX));           \
        float4 nvgi = *reinterpret_cast<const float4*>(gpi + (NX));           \
        CSTEP((Q)+0, vgc.x, vgic.x, 0); CSTEP((Q)+1, vgc.y, vgic.y, 0);       \
        CSTEP((Q)+2, vgc.z, vgic.z, 0);                                       \
        CSTEP((Q)+3, vgc.w, vgic.w, ((Q) == 4 || (Q) == 12));                 \
        vgc = nvg; vgic = nvgi;                                               \
    }

#define TS(PP, GV, GIV)                                                       \
    if ((PP) < rem) {                                                         \
        CSTEP(PP, GV, GIV, ((PP) == 7 || (PP) == 15));                        \
        if ((PP) == rem - 1) Afin = acur;                                     \
        if ((((PP) & 7) == 7) && ((PP) < rem - 1)) CRENORM();                 \
    }

#define TQ(Q)                                                                 \
    if ((Q) < rem) {                                                          \
        float4 vg  = *reinterpret_cast<const float4*>(gpg + tl0 + (Q));       \
        float4 vgi = *reinterpret_cast<const float4*>(gpi + tl0 + (Q));       \
        TS((Q)+0, vg.x, vgi.x); TS((Q)+1, vg.y, vgi.y);                       \
        TS((Q)+2, vg.z, vgi.z); TS((Q)+3, vg.w, vgi.w);                       \
    }

__global__ __launch_bounds__(448) void chunk_kernel(
    const float* __restrict__ emitA, const float* __restrict__ emitB,
    const int* __restrict__ lengths, const float* __restrict__ trans,
    const float* __restrict__ dur, __hip_bfloat16* __restrict__ Mout,
    float* __restrict__ Rout, float* __restrict__ ezOut,
    float* __restrict__ Zmx)
{
    __shared__ float gg[2 * 5 * GW];   // [g|gi][class][GW]
    __shared__ float I16s[C_][16];     // suffix products of gi at chunk end
    __shared__ float zsh[80];
    __shared__ float zred;
    int blk = blockIdx.x;
    int b = blk >> 6, k = blk & (NC_ - 1);
    int len = lengths[b];
    int s = (k * len) >> 6;
    int e = ((k + 1) * len) >> 6;
    int L = e - s;                       // 64..128
    int tid = threadIdx.x;

    for (int i = tid; i < C_ * GSPAN; i += 448) {
        int cc = i / GSPAN, j = i - cc * GSPAN;
        int pos = s - 16 + j;
        float g = 1.0f, gi = 1.0f;
        if (pos >= 0 && j < 16 + L) {
            size_t gx = ((size_t)b * C_ + cc) * T_ + pos;
            float ev = emitA[gx] + emitB[gx];
            g = __expf(ev); gi = __expf(-ev);
        }
        gg[cc * GW + j] = g;
        gg[GIOFF + cc * GW + j] = gi;
    }
    __syncthreads();
    // I16s[c][j] = prod_{i2=0}^{j-1} gi[16 + L-1-i2]
    if (tid < C_ * 16) {
        int cc = tid >> 4, j = tid & 15;
        float run = 1.0f;
        for (int i2 = 0; i2 < j; ++i2)
            run *= gg[GIOFF + cc * GW + 16 + L - 1 - i2];
        I16s[cc][j] = run;
    }
    __syncthreads();

    int lane = tid & 63, wv = tid >> 6;  // 7 waves
    int row16 = lane >> 4;               // DPP row 0..3
    int sub = lane & 15;                 // 0..15; 15 idle
    int c = sub / 3; if (c > 4) c = 4;   // class
    int colIdx = sub - c * 3;            // 0..2 (sub15 -> 3)
    int col = wv * 12 + row16 * 3 + colIdx;
    bool active = (sub < 15) && (col < 80);

    const float* gpg = &gg[c * GW + 16];
    const float* gpi = &gg[GIOFF + c * GW + 16];

    float ed[K_];
    #pragma unroll
    for (int j = 0; j < K_; ++j) ed[j] = __expf(dur[c * K_ + j]);

    float gate = active ? 1.0f : 0.0f;
    float eTf[C_];
    #pragma unroll
    for (int x = 0; x < C_; ++x) eTf[x] = __expf(trans[x * C_ + c]) * gate;
    float wSelf = eTf[c];
    float wL1 = (c >= 1) ? eTf[c-1] : 0.0f;
    float wL2 = (c >= 2) ? eTf[c-2] : 0.0f;
    float wL3 = (c >= 3) ? eTf[c-3] : 0.0f;
    float wL4 = (c >= 4) ? eTf[c-4] : 0.0f;
    float wR1 = (c + 1 <= 4) ? eTf[c+1] : 0.0f;
    float wR2 = (c + 2 <= 4) ? eTf[c+2] : 0.0f;
    float wR3 = (c + 3 <= 4) ? eTf[c+3] : 0.0f;
    float wR4 = (c + 4 <= 4) ? eTf[c+4] : 0.0f;
    float a0w0 = (c == 0) ? gate : 0.0f;
    float a0w1 = (c == 1) ? gate : 0.0f;
    float a0w2 = (c == 2) ? gate : 0.0f;
    float a0w3 = (c == 3) ? gate : 0.0f;
    float a0w4 = (c == 4) ? gate : 0.0f;

    int j0 = col / 5, c0 = col - j0 * 5;
    float sv = 1.0f;
    for (int j = 16 - j0; j < 16; ++j) sv *= gg[c0 * GW + j];
    float W[K_];
    #pragma unroll
    for (int q = 0; q < K_; ++q)
        W[q] = (active && c == c0 && q == j0) ? sv : 0.0f;

    float P = 1.0f, iP = 1.0f, z = 0.0f;
    float acur = 0.0f, Afin = 0.0f, A0v = 0.0f;

    int nfull = (L - 1) >> 4;            // 3..7
    int rem = L - (nfull << 4);          // 1..16
    int tl0 = 0;

    float4 vgc  = *reinterpret_cast<const float4*>(gpg);
    float4 vgic = *reinterpret_cast<const float4*>(gpi);
    for (int bi = 0; bi < nfull; ++bi) {
        QBLKP(0, tl0 + 4); QBLKP(4, tl0 + 8);
        CRENORM();
        QBLKP(8, tl0 + 12); QBLKP(12, tl0 + 16);
        CRENORM();
        tl0 += 16;
    }
    TQ(0); TQ(4); TQ(8); TQ(12);

    size_t cid = (size_t)b * NC_ + k;
    int pn = L & 15;
    if (k == NC_ - 1) {
        if (active) {
            Rout[(size_t)b * 400 + (size_t)col * C_ + c] = Afin;
            if (c == 0) zsh[col] = z;
        }
    } else {
        // column-normalized M; column max via the same DPP shifts (both dirs)
        float lm = 0.0f;
        if (active) {
            #pragma unroll
            for (int slot = 0; slot < K_; ++slot) {
                int j = (slot + pn) & 15;
                float vv = W[slot] * P * I16s[c][j];
                W[slot] = vv;
                lm = fmaxf(lm, vv);
            }
        }
        float m = lm;
        m = fmaxf(m, dppf<0x103>(lm)); m = fmaxf(m, dppf<0x106>(lm));
        m = fmaxf(m, dppf<0x109>(lm)); m = fmaxf(m, dppf<0x10C>(lm));
        m = fmaxf(m, dppf<0x113>(lm)); m = fmaxf(m, dppf<0x116>(lm));
        m = fmaxf(m, dppf<0x119>(lm)); m = fmaxf(m, dppf<0x11C>(lm));
        float cmax = m;
        float inv = (cmax > 0.0f) ? 1.0f / cmax : 0.0f;
        if (active) {
            __hip_bfloat16* mb = Mout + cid * 6400;
            if (k < NFW) {
                // fwd-range: TRANSPOSED storage MT[rowOut*80 + colIn]
                #pragma unroll
                for (int slot = 0; slot < K_; ++slot) {
                    int j = (slot + pn) & 15;
                    mb[(j * C_ + c) * 80 + col] = __float2bfloat16(W[slot] * inv);
                }
            } else {
                // bwd-range: col-major M[colIn*80 + rowOut]
                #pragma unroll
                for (int slot = 0; slot < K_; ++slot) {
                    int j = (slot + pn) & 15;
                    mb[(size_t)col * 80 + j * C_ + c] = __float2bfloat16(W[slot] * inv);
                }
            }
            if (c == 0) zsh[col] = (cmax > 0.0f) ? z + __logf(cmax) : -3.0e38f;
        }
    }
    __syncthreads();
    if (tid < 64) {
        float m = zsh[tid];
        if (tid < 16) m = fmaxf(m, zsh[tid + 64]);
        #pragma unroll
        for (int off = 32; off; off >>= 1) m = fmaxf(m, __shfl_xor(m, off, 64));
        if (tid == 0) zred = m;
    }
    __syncthreads();
    float zm = zred;
    if (tid == 0) Zmx[cid] = zm;
    if (active && c == 0) ezOut[cid * 80 + col] = __expf(zsh[col] - zm);
}

// ---------------- Kernel D: chains — reg-resident M slices, renorm every 8 ----------------
__global__ __launch_bounds__(320) void chain_kernel(
    const __hip_bfloat16* __restrict__ Mst, const float* __restrict__ ezZ,
    const float* __restrict__ Zmx, const float* __restrict__ Rst,
    const float* __restrict__ startv, float* __restrict__ Uvec,
    float* __restrict__ Xvec, float* __restrict__ Zu, float* __restrict__ Zx)
{
    __shared__ __align__(16) float vin[80];
    __shared__ __align__(16) float sv[80];
    __shared__ __align__(16) float part[4][80];
    __shared__ float red;
    int b = blockIdx.x >> 1;
    int dir = blockIdx.x & 1;
    int tid = threadIdx.x;
    int grp = tid / 80, r = tid - grp * 80;
    int base = grp * 20;
    int moff = r * 40 + grp * 10;       // dword offset of this thread's slice
    float Z = 0.0f;
    int nmat = (dir == 0) ? NFW : (NC_ - 1 - NFW);   // 31 fwd, 32 bwd

    if (dir == 0) {
        if (tid < 80) vin[tid] = (tid < C_) ? __expf(startv[tid]) : 0.0f;
        __syncthreads();
    } else {
        size_t last = (size_t)b * NC_ + NC_ - 1;
        if (tid < 80) {
            const float* R = Rst + (size_t)b * 400 + (size_t)tid * C_;
            float rs = ((R[0] + R[1]) + (R[2] + R[3])) + R[4];
            sv[tid] = rs * ezZ[last * 80 + tid];
        }
        __syncthreads();
        if (tid < 64) {
            float m = sv[tid];
            if (tid < 16) m = fmaxf(m, sv[tid + 64]);
            #pragma unroll
            for (int o = 32; o; o >>= 1) m = fmaxf(m, __shfl_xor(m, o, 64));
            if (tid == 0) red = m;
        }
        __syncthreads();
        float rm = red;
        if (tid < 80) vin[tid] = sv[tid] / rm;
        Z = Zmx[b * NC_ + NC_ - 1] + __logf(rm);
        __syncthreads();
    }

    // prefetch first matrix slice
    int k0 = (dir == 0) ? 0 : NC_ - 2;
    unsigned int pm[10];
    {
        const unsigned int* mg = (const unsigned int*)(Mst + (size_t)(b * NC_ + k0) * 6400);
        #pragma unroll
        for (int i = 0; i < 10; ++i) pm[i] = mg[moff + i];
    }

    for (int it = 0; it < nmat; ++it) {
        int k  = (dir == 0) ? it : (NC_ - 2 - it);
        int kn = (dir == 0) ? k + 1 : k - 1;
        bool more = (it + 1 < nmat);
        size_t cid = (size_t)b * NC_ + k;

        float ezv = 0.0f;
        if (tid < 80) {
            ezv = ezZ[cid * 80 + tid];
            sv[tid] = (dir == 0) ? vin[tid] * ezv : vin[tid];
        }
        __syncthreads();

        unsigned int mu[10];
        if (more) {
            const unsigned int* mg = (const unsigned int*)(Mst + ((size_t)b * NC_ + kn) * 6400);
            #pragma unroll
            for (int i = 0; i < 10; ++i) mu[i] = mg[moff + i];
        }

        float xv[20];
        #pragma unroll
        for (int i2 = 0; i2 < 5; ++i2)
            *reinterpret_cast<float4*>(&xv[4 * i2]) =
                *reinterpret_cast<const float4*>(&sv[base + 4 * i2]);
        float p = 0.0f;
        #pragma unroll
        for (int i = 0; i < 10; ++i) {
            unsigned int u = pm[i];
            p = fmaf(bf16lo(u), xv[2 * i + 0], p);
            p = fmaf(bf16hi(u), xv[2 * i + 1], p);
        }
        part[grp][r] = p;
        __syncthreads();

        Z += Zmx[cid];
        bool rn = ((it & 7) == 7) || (it == nmat - 1);
        if (tid < 80) {
            float nv = (part[0][tid] + part[1][tid]) + (part[2][tid] + part[3][tid]);
            if (dir == 1) nv *= ezv;
            if (rn) sv[tid] = nv; else vin[tid] = nv;
        }
        if (rn) {
            __syncthreads();
            if (tid < 64) {
                float m = sv[tid];
                if (tid < 16) m = fmaxf(m, sv[tid + 64]);
                #pragma unroll
                for (int o = 32; o; o >>= 1) m = fmaxf(m, __shfl_xor(m, o, 64));
                if (tid == 0) red = m;
            }
            __syncthreads();
            float rm = red;
            if (tid < 80) vin[tid] = sv[tid] / rm;
            Z += __logf(rm);
        }
        #pragma unroll
        for (int i = 0; i < 10; ++i) pm[i] = mu[i];
    }

    if (dir == 0) {
        if (tid < 80) Xvec[b * 80 + tid] = vin[tid];
        if (tid == 0) Zx[b] = Z;
    } else {
        if (tid < 80) Uvec[b * 80 + tid] = vin[tid];
        if (tid == 0) Zu[b] = Z;
    }
}

// ---------------- Kernel E: meet -> partition ----------------
__global__ __launch_bounds__(512) void meet_kernel(
    const float* __restrict__ Uvec, const float* __restrict__ Xvec,
    const float* __restrict__ Zu, const float* __restrict__ Zx,
    float* __restrict__ partition)
{
    int tid = threadIdx.x;
    int b = tid >> 6, lane = tid & 63;
    float v = Uvec[b * 80 + lane] * Xvec[b * 80 + lane];
    if (lane < 16) v += Uvec[b * 80 + 64 + lane] * Xvec[b * 80 + 64 + lane];
    #pragma unroll
    for (int off = 32; off; off >>= 1) v += __shfl_xor(v, off, 64);
    if (lane == 0) partition[b] = Zu[b] + Zx[b] + __logf(v);
}

extern "C" void kernel_launch(void* const* d_in, const int* in_sizes, int n_in,
                              void* d_out, int out_size, void* d_ws, size_t ws_size,
                              hipStream_t stream) {
    (void)in_sizes; (void)n_in; (void)out_size; (void)ws_size;
    const float* seq    = (const float*)d_in[0];
    const int*   lens   = (const int*)  d_in[1];
    const float* W_enc  = (const float*)d_in[2];
    const float* b_enc  = (const float*)d_in[3];
    const float* W_proj = (const float*)d_in[4];
    const float* b_proj = (const float*)d_in[5];
    const float* trans  = (const float*)d_in[6];
    const float* startv = (const float*)d_in[7];
    const float* dur    = (const float*)d_in[8];

    float* out       = (float*)d_out;
    float* partition = out;
    float* cum       = out + B_;

    float* emitA = (float*)d_ws;                              // B*C*T f32
    float* emitB = emitA + (size_t)B_ * C_ * T_;              // B*C*T f32
    __hip_bfloat16* Mst = (__hip_bfloat16*)(emitB + (size_t)B_ * C_ * T_);  // B*NC*6400 bf16
    float* Rst = (float*)(Mst + (size_t)B_ * NC_ * 6400);     // B*400 f32 (last chunk only)
    float* ezS = Rst + (size_t)B_ * 400;                      // B*NC*80 f32
    float* Zmx = ezS + (size_t)B_ * NC_ * 80;                 // B*NC f32
    float* PA  = Zmx + (size_t)B_ * NC_;                      // 2*B*NTILE*C f32
    float* Uv  = PA  + 2 * B_ * NTILE * C_;                   // B*80
    float* Xv  = Uv  + B_ * 80;                               // B*80
    float* Zu  = Xv  + B_ * 80;                               // B
    float* Zx  = Zu  + B_;                                    // B

    encoder_kernel<<<512, 256, 0, stream>>>(seq, W_enc, b_enc, W_proj, b_proj, emitA, emitB, PA);
    chunk_kernel<<<B_ * NC_, 448, 0, stream>>>(emitA, emitB, lens, trans, dur, Mst, Rst, ezS, Zmx);
    cumwrite_kernel<<<B_ * C_ * NTILE, 64, 0, stream>>>(emitA, emitB, PA, cum);
    chain_kernel<<<16, 320, 0, stream>>>(Mst, ezS, Zmx, Rst, startv, Uv, Xv, Zu, Zx);
    meet_kernel<<<1, 512, 0, stream>>>(Uv, Xv, Zu, Zx, partition);
}

// Round 19
// 84.827 us; speedup vs baseline: 1.1954x; 1.1954x over previous
//
#include <hip/hip_runtime.h>
#include <hip/hip_bf16.h>

#define B_ 8
#define T_ 8192
#define HID_ 256
#define C_ 5
#define K_ 16
#define NC_ 32    // chunks per batch
#define NTILE 32  // 256-position tiles per batch (cumsum pipeline)
#define GSPAN 272 // 16 pre-window + LMAX(256)
#define GW 276    // padded LDS row stride (floats)
#define GIOFF (5 * GW)
#define NFW 15    // fwd-chain matrices k=0..14 (stored TRANSPOSED); bwd: R(31), M30..M15

__device__ __forceinline__ float gelu_tanh(float x) {
    float u = 0.7978845608028654f * (x + 0.044715f * x * x * x);
    float e = __expf(2.0f * u);
    float th = 1.0f - 2.0f / (e + 1.0f);
    return 0.5f * x * (1.0f + th);
}

__device__ __forceinline__ float bf16lo(unsigned int u) {
    return __uint_as_float(u << 16);
}
__device__ __forceinline__ float bf16hi(unsigned int u) {
    return __uint_as_float(u & 0xffff0000u);
}
// DPP row shift (pure VALU): row_shr:N (0x110|N) = dst n <- src n-N (lower);
// row_shl:N (0x100|N) = dst n <- src n+N (higher). bound_ctrl=true -> 0 OOB.
template <int CTRL>
__device__ __forceinline__ float dppf(float x) {
    return __uint_as_float((unsigned int)__builtin_amdgcn_mov_dpp(
        (int)__float_as_uint(x), CTRL, 0xF, 0xF, true));
}

// ---------------- Kernel A: encoder (hidden split) -> emitA/emitB + per-tile class sums ----------------
__global__ __launch_bounds__(256) void encoder_kernel(
    const float* __restrict__ seq, const float* __restrict__ W_enc,
    const float* __restrict__ b_enc, const float* __restrict__ W_proj,
    const float* __restrict__ b_proj, float* __restrict__ emitA,
    float* __restrict__ emitB, float* __restrict__ PA)
{
    __shared__ float4 we[128];
    __shared__ float  be[128];
    __shared__ float  wp[128 * C_];
    __shared__ float  prd[4][C_];
    int tid = threadIdx.x;
    int half = blockIdx.x >> 8;
    int blk  = blockIdx.x & 255;
    int h0 = half * 128;
    if (tid < 128) {
        int h = h0 + tid;
        we[tid] = make_float4(W_enc[0*HID_+h], W_enc[1*HID_+h], W_enc[2*HID_+h], W_enc[3*HID_+h]);
        be[tid] = b_enc[h];
    }
    for (int i = tid; i < 128 * C_; i += 256) wp[i] = W_proj[h0 * C_ + i];
    __syncthreads();
    int b = blk >> 5;
    int tile = blk & 31;
    int t = tile * 256 + tid;
    float4 s = reinterpret_cast<const float4*>(seq)[(size_t)b * T_ + t];
    float a0, a1, a2, a3, a4;
    if (half == 0) { a0 = b_proj[0]; a1 = b_proj[1]; a2 = b_proj[2]; a3 = b_proj[3]; a4 = b_proj[4]; }
    else           { a0 = a1 = a2 = a3 = a4 = 0.0f; }
    #pragma unroll 8
    for (int h = 0; h < 128; ++h) {
        float4 w = we[h];
        float pre = be[h] + s.x*w.x + s.y*w.y + s.z*w.z + s.w*w.w;
        float hd = gelu_tanh(pre);
        a0 = fmaf(hd, wp[h*C_+0], a0);
        a1 = fmaf(hd, wp[h*C_+1], a1);
        a2 = fmaf(hd, wp[h*C_+2], a2);
        a3 = fmaf(hd, wp[h*C_+3], a3);
        a4 = fmaf(hd, wp[h*C_+4], a4);
    }
    float* em = half ? emitB : emitA;
    size_t base = (size_t)b * C_ * T_ + t;
    em[base + 0*T_] = a0;
    em[base + 1*T_] = a1;
    em[base + 2*T_] = a2;
    em[base + 3*T_] = a3;
    em[base + 4*T_] = a4;
    float s0 = a0, s1 = a1, s2 = a2, s3 = a3, s4 = a4;
    #pragma unroll
    for (int off = 1; off < 64; off <<= 1) {
        s0 += __shfl_xor(s0, off, 64);
        s1 += __shfl_xor(s1, off, 64);
        s2 += __shfl_xor(s2, off, 64);
        s3 += __shfl_xor(s3, off, 64);
        s4 += __shfl_xor(s4, off, 64);
    }
    int lane = tid & 63, wv = tid >> 6;
    if (lane == 0) { prd[wv][0]=s0; prd[wv][1]=s1; prd[wv][2]=s2; prd[wv][3]=s3; prd[wv][4]=s4; }
    __syncthreads();
    if (tid < C_) {
        float t4 = (prd[0][tid] + prd[1][tid]) + (prd[2][tid] + prd[3][tid]);
        PA[((half * B_ + b) * NTILE + tile) * C_ + tid] = t4;
    }
}

// ---------------- Kernel B: cum writer (one block per (b,c,tile)) ----------------
__global__ __launch_bounds__(64) void cumwrite_kernel(
    const float* __restrict__ emitA, const float* __restrict__ emitB,
    const float* __restrict__ PA, float* __restrict__ cum)
{
    int bx = blockIdx.x;
    int tile = bx & (NTILE - 1);
    int bc = bx >> 5;
    int b = bc / C_, c = bc - b * C_;
    int lane = threadIdx.x;
    float v = 0.0f;
    if (lane < NTILE && lane < tile)
        v = PA[((0 * B_ + b) * NTILE + lane) * C_ + c]
          + PA[((1 * B_ + b) * NTILE + lane) * C_ + c];
    #pragma unroll
    for (int o = 32; o; o >>= 1) v += __shfl_xor(v, o, 64);
    const float* eA = emitA + ((size_t)b * C_ + c) * T_;
    const float* eB = emitB + ((size_t)b * C_ + c) * T_;
    float* cb = cum + (size_t)b * (T_ + 1) * C_;
    if (tile == 0 && lane == 0) cb[c] = 0.0f;
    float carry = v;
    #pragma unroll
    for (int i = 0; i < 4; ++i) {
        int idx = tile * 256 + i * 64 + lane;
        float e = eA[idx] + eB[idx];
        float si = e;
        #pragma unroll
        for (int o = 1; o < 64; o <<= 1) {
            float n = __shfl_up(si, o, 64);
            if (lane >= o) si += n;
        }
        cb[(size_t)(idx + 1) * C_ + c] = carry + si;
        carry += __shfl(si, 63, 64);
    }
}

// ---------------- Kernel C: per-chunk 80x80 transfer matrices (DPP + prefetch) ----------------
#define DOT16(PP, OUT)                                                        \
    {                                                                         \
        float q0, q1, q2, q3;                                                 \
        q0 = W[0] * ed[(0 + (PP)) & 15];                                      \
        q1 = W[1] * ed[(1 + (PP)) & 15];                                      \
        q2 = W[2] * ed[(2 + (PP)) & 15];                                      \
        q3 = W[3] * ed[(3 + (PP)) & 15];                                      \
        q0 = fmaf(W[4],  ed[(4  + (PP)) & 15], q0);                           \
        q1 = fmaf(W[5],  ed[(5  + (PP)) & 15], q1);                           \
        q2 = fmaf(W[6],  ed[(6  + (PP)) & 15], q2);                           \
        q3 = fmaf(W[7],  ed[(7  + (PP)) & 15], q3);                           \
        q0 = fmaf(W[8],  ed[(8  + (PP)) & 15], q0);                           \
        q1 = fmaf(W[9],  ed[(9  + (PP)) & 15], q1);                           \
        q2 = fmaf(W[10], ed[(10 + (PP)) & 15], q2);                           \
        q3 = fmaf(W[11], ed[(11 + (PP)) & 15], q3);                           \
        q0 = fmaf(W[12], ed[(12 + (PP)) & 15], q0);                           \
        q1 = fmaf(W[13], ed[(13 + (PP)) & 15], q1);                           \
        q2 = fmaf(W[14], ed[(14 + (PP)) & 15], q2);                           \
        q3 = fmaf(W[15], ed[(15 + (PP)) & 15], q3);                           \
        OUT = (q0 + q1) + (q2 + q3);                                          \
    }

#define CSTEP(PP, GV, GIV, CAP)                                               \
    {                                                                         \
        P *= (GV); iP *= (GIV);                                               \
        float dtv;                                                            \
        DOT16(PP, dtv);                                                       \
        acur = P * dtv;                                                       \
        float r3  = dppf<0x113>(acur);  /* class c-1 */                       \
        float r6  = dppf<0x116>(acur);  /* class c-2 */                       \
        float r9  = dppf<0x119>(acur);  /* class c-3 */                       \
        float r12 = dppf<0x11C>(acur);  /* class c-4 */                       \
        float l3  = dppf<0x103>(acur);  /* class c+1 */                       \
        float l6  = dppf<0x106>(acur);  /* class c+2 */                       \
        float l9  = dppf<0x109>(acur);  /* class c+3 */                       \
        float l12 = dppf<0x10C>(acur);  /* class c+4 */                       \
        if (CAP) {                                                            \
            A0v = fmaf(a0w0, acur, fmaf(a0w1, r3, fmaf(a0w2, r6,              \
                  fmaf(a0w3, r9, a0w4 * r12))));                              \
        }                                                                     \
        float s01 = fmaf(wSelf, acur, wL1 * r3);                              \
        float s23 = fmaf(wL2, r6, wL3 * r9);                                  \
        float s45 = fmaf(wL4, r12, wR1 * l3);                                 \
        float s67 = fmaf(wR2, l6, wR3 * l9);                                  \
        float Sn = ((s01 + s23) + (s45 + s67)) + wR4 * l12;                   \
        W[15 - (PP)] = Sn * iP;                                               \
    }

#define CRENORM()                                                             \
    {                                                                         \
        bool ok = (A0v > 1e-30f);                                             \
        float rr = ok ? __builtin_amdgcn_rcpf(A0v) : 1.0f;                    \
        float lz = ok ? __logf(A0v) : 0.0f;                                   \
        float f = P * rr;                                                     \
        _Pragma("unroll") for (int q = 0; q < 16; ++q) W[q] *= f;             \
        P = 1.0f; iP = 1.0f; z += lz;                                         \
    }

// prefetched-window QBLK: consume vgc/vgic, prefetch next window at NX
#define QBLKP(Q, NX)                                                          \
    {                                                                         \
        float4 nvg  = *reinterpret_cast<const float4*>(gpg + (NX));           \
        float4 nvgi = *reinterpret_cast<const float4*>(gpi + (NX));           \
        CSTEP((Q)+0, vgc.x, vgic.x, 0); CSTEP((Q)+1, vgc.y, vgic.y, 0);       \
        CSTEP((Q)+2, vgc.z, vgic.z, 0);                                       \
        CSTEP((Q)+3, vgc.w, vgic.w, ((Q) == 4 || (Q) == 12));                 \
        vgc = nvg; vgic = nvgi;                                               \
    }

#define TS(PP, GV, GIV)                                                       \
    if ((PP) < rem) {                                                         \
        CSTEP(PP, GV, GIV, ((PP) == 7 || (PP) == 15));                        \
        if ((PP) == rem - 1) Afin = acur;                                     \
        if ((((PP) & 7) == 7) && ((PP) < rem - 1)) CRENORM();                 \
    }

#define TQ(Q)                                                                 \
    if ((Q) < rem) {                                                          \
        float4 vg  = *reinterpret_cast<const float4*>(gpg + tl0 + (Q));       \
        float4 vgi = *reinterpret_cast<const float4*>(gpi + tl0 + (Q));       \
        TS((Q)+0, vg.x, vgi.x); TS((Q)+1, vg.y, vgi.y);                       \
        TS((Q)+2, vg.z, vgi.z); TS((Q)+3, vg.w, vgi.w);                       \
    }

__global__ __launch_bounds__(448) void chunk_kernel(
    const float* __restrict__ emitA, const float* __restrict__ emitB,
    const int* __restrict__ lengths, const float* __restrict__ trans,
    const float* __restrict__ dur, __hip_bfloat16* __restrict__ Mout,
    float* __restrict__ Rout, float* __restrict__ ezOut,
    float* __restrict__ Zmx)
{
    __shared__ float gg[2 * 5 * GW];   // [g|gi][class][GW]
    __shared__ float I16s[C_][16];     // suffix products of gi at chunk end
    __shared__ float zsh[80];
    __shared__ float zred;
    int blk = blockIdx.x;
    int b = blk >> 5, k = blk & (NC_ - 1);
    int len = lengths[b];
    int s = (k * len) >> 5;
    int e = ((k + 1) * len) >> 5;
    int L = e - s;                       // 128..256
    int tid = threadIdx.x;

    for (int i = tid; i < C_ * GSPAN; i += 448) {
        int cc = i / GSPAN, j = i - cc * GSPAN;
        int pos = s - 16 + j;
        float g = 1.0f, gi = 1.0f;
        if (pos >= 0 && j < 16 + L) {
            size_t gx = ((size_t)b * C_ + cc) * T_ + pos;
            float ev = emitA[gx] + emitB[gx];
            g = __expf(ev); gi = __expf(-ev);
        }
        gg[cc * GW + j] = g;
        gg[GIOFF + cc * GW + j] = gi;
    }
    __syncthreads();
    // I16s[c][j] = prod_{i2=0}^{j-1} gi[16 + L-1-i2]
    if (tid < C_ * 16) {
        int cc = tid >> 4, j = tid & 15;
        float run = 1.0f;
        for (int i2 = 0; i2 < j; ++i2)
            run *= gg[GIOFF + cc * GW + 16 + L - 1 - i2];
        I16s[cc][j] = run;
    }
    __syncthreads();

    int lane = tid & 63, wv = tid >> 6;  // 7 waves
    int row16 = lane >> 4;               // DPP row 0..3
    int sub = lane & 15;                 // 0..15; 15 idle
    int c = sub / 3; if (c > 4) c = 4;   // class
    int colIdx = sub - c * 3;            // 0..2 (sub15 -> 3)
    int col = wv * 12 + row16 * 3 + colIdx;
    bool active = (sub < 15) && (col < 80);

    const float* gpg = &gg[c * GW + 16];
    const float* gpi = &gg[GIOFF + c * GW + 16];

    float ed[K_];
    #pragma unroll
    for (int j = 0; j < K_; ++j) ed[j] = __expf(dur[c * K_ + j]);

    float gate = active ? 1.0f : 0.0f;
    float eTf[C_];
    #pragma unroll
    for (int x = 0; x < C_; ++x) eTf[x] = __expf(trans[x * C_ + c]) * gate;
    float wSelf = eTf[c];
    float wL1 = (c >= 1) ? eTf[c-1] : 0.0f;
    float wL2 = (c >= 2) ? eTf[c-2] : 0.0f;
    float wL3 = (c >= 3) ? eTf[c-3] : 0.0f;
    float wL4 = (c >= 4) ? eTf[c-4] : 0.0f;
    float wR1 = (c + 1 <= 4) ? eTf[c+1] : 0.0f;
    float wR2 = (c + 2 <= 4) ? eTf[c+2] : 0.0f;
    float wR3 = (c + 3 <= 4) ? eTf[c+3] : 0.0f;
    float wR4 = (c + 4 <= 4) ? eTf[c+4] : 0.0f;
    float a0w0 = (c == 0) ? gate : 0.0f;
    float a0w1 = (c == 1) ? gate : 0.0f;
    float a0w2 = (c == 2) ? gate : 0.0f;
    float a0w3 = (c == 3) ? gate : 0.0f;
    float a0w4 = (c == 4) ? gate : 0.0f;

    int j0 = col / 5, c0 = col - j0 * 5;
    float sv = 1.0f;
    for (int j = 16 - j0; j < 16; ++j) sv *= gg[c0 * GW + j];
    float W[K_];
    #pragma unroll
    for (int q = 0; q < K_; ++q)
        W[q] = (active && c == c0 && q == j0) ? sv : 0.0f;

    float P = 1.0f, iP = 1.0f, z = 0.0f;
    float acur = 0.0f, Afin = 0.0f, A0v = 0.0f;

    int nfull = (L - 1) >> 4;            // 7..15
    int rem = L - (nfull << 4);          // 1..16
    int tl0 = 0;

    float4 vgc  = *reinterpret_cast<const float4*>(gpg);
    float4 vgic = *reinterpret_cast<const float4*>(gpi);
    for (int bi = 0; bi < nfull; ++bi) {
        QBLKP(0, tl0 + 4); QBLKP(4, tl0 + 8);
        CRENORM();
        QBLKP(8, tl0 + 12); QBLKP(12, tl0 + 16);
        CRENORM();
        tl0 += 16;
    }
    TQ(0); TQ(4); TQ(8); TQ(12);

    size_t cid = (size_t)b * NC_ + k;
    int pn = L & 15;
    if (k == NC_ - 1) {
        if (active) {
            Rout[(size_t)b * 400 + (size_t)col * C_ + c] = Afin;
            if (c == 0) zsh[col] = z;
        }
    } else {
        // column-normalized M; column max via the same DPP shifts (both dirs)
        float lm = 0.0f;
        if (active) {
            #pragma unroll
            for (int slot = 0; slot < K_; ++slot) {
                int j = (slot + pn) & 15;
                float vv = W[slot] * P * I16s[c][j];
                W[slot] = vv;
                lm = fmaxf(lm, vv);
            }
        }
        float m = lm;
        m = fmaxf(m, dppf<0x103>(lm)); m = fmaxf(m, dppf<0x106>(lm));
        m = fmaxf(m, dppf<0x109>(lm)); m = fmaxf(m, dppf<0x10C>(lm));
        m = fmaxf(m, dppf<0x113>(lm)); m = fmaxf(m, dppf<0x116>(lm));
        m = fmaxf(m, dppf<0x119>(lm)); m = fmaxf(m, dppf<0x11C>(lm));
        float cmax = m;
        float inv = (cmax > 0.0f) ? 1.0f / cmax : 0.0f;
        if (active) {
            __hip_bfloat16* mb = Mout + cid * 6400;
            if (k < NFW) {
                // fwd-range: TRANSPOSED storage MT[rowOut*80 + colIn]
                #pragma unroll
                for (int slot = 0; slot < K_; ++slot) {
                    int j = (slot + pn) & 15;
                    mb[(j * C_ + c) * 80 + col] = __float2bfloat16(W[slot] * inv);
                }
            } else {
                // bwd-range: col-major M[colIn*80 + rowOut]
                #pragma unroll
                for (int slot = 0; slot < K_; ++slot) {
                    int j = (slot + pn) & 15;
                    mb[(size_t)col * 80 + j * C_ + c] = __float2bfloat16(W[slot] * inv);
                }
            }
            if (c == 0) zsh[col] = (cmax > 0.0f) ? z + __logf(cmax) : -3.0e38f;
        }
    }
    __syncthreads();
    if (tid < 64) {
        float m = zsh[tid];
        if (tid < 16) m = fmaxf(m, zsh[tid + 64]);
        #pragma unroll
        for (int off = 32; off; off >>= 1) m = fmaxf(m, __shfl_xor(m, off, 64));
        if (tid == 0) zred = m;
    }
    __syncthreads();
    float zm = zred;
    if (tid == 0) Zmx[cid] = zm;
    if (active && c == 0) ezOut[cid * 80 + col] = __expf(zsh[col] - zm);
}

// ---------------- Kernel D: chains — reg-resident M slices, renorm every 8 ----------------
__global__ __launch_bounds__(320) void chain_kernel(
    const __hip_bfloat16* __restrict__ Mst, const float* __restrict__ ezZ,
    const float* __restrict__ Zmx, const float* __restrict__ Rst,
    const float* __restrict__ startv, float* __restrict__ Uvec,
    float* __restrict__ Xvec, float* __restrict__ Zu, float* __restrict__ Zx)
{
    __shared__ __align__(16) float vin[80];
    __shared__ __align__(16) float sv[80];
    __shared__ __align__(16) float part[4][80];
    __shared__ float red;
    int b = blockIdx.x >> 1;
    int dir = blockIdx.x & 1;
    int tid = threadIdx.x;
    int grp = tid / 80, r = tid - grp * 80;
    int base = grp * 20;
    int moff = r * 40 + grp * 10;       // dword offset of this thread's slice
    float Z = 0.0f;
    int nmat = (dir == 0) ? NFW : (NC_ - 1 - NFW);   // 15 fwd, 16 bwd

    if (dir == 0) {
        if (tid < 80) vin[tid] = (tid < C_) ? __expf(startv[tid]) : 0.0f;
        __syncthreads();
    } else {
        size_t last = (size_t)b * NC_ + NC_ - 1;
        if (tid < 80) {
            const float* R = Rst + (size_t)b * 400 + (size_t)tid * C_;
            float rs = ((R[0] + R[1]) + (R[2] + R[3])) + R[4];
            sv[tid] = rs * ezZ[last * 80 + tid];
        }
        __syncthreads();
        if (tid < 64) {
            float m = sv[tid];
            if (tid < 16) m = fmaxf(m, sv[tid + 64]);
            #pragma unroll
            for (int o = 32; o; o >>= 1) m = fmaxf(m, __shfl_xor(m, o, 64));
            if (tid == 0) red = m;
        }
        __syncthreads();
        float rm = red;
        if (tid < 80) vin[tid] = sv[tid] / rm;
        Z = Zmx[b * NC_ + NC_ - 1] + __logf(rm);
        __syncthreads();
    }

    // prefetch first matrix slice
    int k0 = (dir == 0) ? 0 : NC_ - 2;
    unsigned int pm[10];
    {
        const unsigned int* mg = (const unsigned int*)(Mst + (size_t)(b * NC_ + k0) * 6400);
        #pragma unroll
        for (int i = 0; i < 10; ++i) pm[i] = mg[moff + i];
    }

    for (int it = 0; it < nmat; ++it) {
        int k  = (dir == 0) ? it : (NC_ - 2 - it);
        int kn = (dir == 0) ? k + 1 : k - 1;
        bool more = (it + 1 < nmat);
        size_t cid = (size_t)b * NC_ + k;

        float ezv = 0.0f;
        if (tid < 80) {
            ezv = ezZ[cid * 80 + tid];
            sv[tid] = (dir == 0) ? vin[tid] * ezv : vin[tid];
        }
        __syncthreads();

        unsigned int mu[10];
        if (more) {
            const unsigned int* mg = (const unsigned int*)(Mst + ((size_t)b * NC_ + kn) * 6400);
            #pragma unroll
            for (int i = 0; i < 10; ++i) mu[i] = mg[moff + i];
        }

        float xv[20];
        #pragma unroll
        for (int i2 = 0; i2 < 5; ++i2)
            *reinterpret_cast<float4*>(&xv[4 * i2]) =
                *reinterpret_cast<const float4*>(&sv[base + 4 * i2]);
        float p = 0.0f;
        #pragma unroll
        for (int i = 0; i < 10; ++i) {
            unsigned int u = pm[i];
            p = fmaf(bf16lo(u), xv[2 * i + 0], p);
            p = fmaf(bf16hi(u), xv[2 * i + 1], p);
        }
        part[grp][r] = p;
        __syncthreads();

        Z += Zmx[cid];
        bool rn = ((it & 7) == 7) || (it == nmat - 1);
        if (tid < 80) {
            float nv = (part[0][tid] + part[1][tid]) + (part[2][tid] + part[3][tid]);
            if (dir == 1) nv *= ezv;
            if (rn) sv[tid] = nv; else vin[tid] = nv;
        }
        if (rn) {
            __syncthreads();
            if (tid < 64) {
                float m = sv[tid];
                if (tid < 16) m = fmaxf(m, sv[tid + 64]);
                #pragma unroll
                for (int o = 32; o; o >>= 1) m = fmaxf(m, __shfl_xor(m, o, 64));
                if (tid == 0) red = m;
            }
            __syncthreads();
            float rm = red;
            if (tid < 80) vin[tid] = sv[tid] / rm;
            Z += __logf(rm);
        }
        #pragma unroll
        for (int i = 0; i < 10; ++i) pm[i] = mu[i];
    }

    if (dir == 0) {
        if (tid < 80) Xvec[b * 80 + tid] = vin[tid];
        if (tid == 0) Zx[b] = Z;
    } else {
        if (tid < 80) Uvec[b * 80 + tid] = vin[tid];
        if (tid == 0) Zu[b] = Z;
    }
}

// ---------------- Kernel E: meet -> partition ----------------
__global__ __launch_bounds__(512) void meet_kernel(
    const float* __restrict__ Uvec, const float* __restrict__ Xvec,
    const float* __restrict__ Zu, const float* __restrict__ Zx,
    float* __restrict__ partition)
{
    int tid = threadIdx.x;
    int b = tid >> 6, lane = tid & 63;
    float v = Uvec[b * 80 + lane] * Xvec[b * 80 + lane];
    if (lane < 16) v += Uvec[b * 80 + 64 + lane] * Xvec[b * 80 + 64 + lane];
    #pragma unroll
    for (int off = 32; off; off >>= 1) v += __shfl_xor(v, off, 64);
    if (lane == 0) partition[b] = Zu[b] + Zx[b] + __logf(v);
}

extern "C" void kernel_launch(void* const* d_in, const int* in_sizes, int n_in,
                              void* d_out, int out_size, void* d_ws, size_t ws_size,
                              hipStream_t stream) {
    (void)in_sizes; (void)n_in; (void)out_size; (void)ws_size;
    const float* seq    = (const float*)d_in[0];
    const int*   lens   = (const int*)  d_in[1];
    const float* W_enc  = (const float*)d_in[2];
    const float* b_enc  = (const float*)d_in[3];
    const float* W_proj = (const float*)d_in[4];
    const float* b_proj = (const float*)d_in[5];
    const float* trans  = (const float*)d_in[6];
    const float* startv = (const float*)d_in[7];
    const float* dur    = (const float*)d_in[8];

    float* out       = (float*)d_out;
    float* partition = out;
    float* cum       = out + B_;

    float* emitA = (float*)d_ws;                              // B*C*T f32
    float* emitB = emitA + (size_t)B_ * C_ * T_;              // B*C*T f32
    __hip_bfloat16* Mst = (__hip_bfloat16*)(emitB + (size_t)B_ * C_ * T_);  // B*NC*6400 bf16
    float* Rst = (float*)(Mst + (size_t)B_ * NC_ * 6400);     // B*400 f32 (last chunk only)
    float* ezS = Rst + (size_t)B_ * 400;                      // B*NC*80 f32
    float* Zmx = ezS + (size_t)B_ * NC_ * 80;                 // B*NC f32
    float* PA  = Zmx + (size_t)B_ * NC_;                      // 2*B*NTILE*C f32
    float* Uv  = PA  + 2 * B_ * NTILE * C_;                   // B*80
    float* Xv  = Uv  + B_ * 80;                               // B*80
    float* Zu  = Xv  + B_ * 80;                               // B
    float* Zx  = Zu  + B_;                                    // B

    encoder_kernel<<<512, 256, 0, stream>>>(seq, W_enc, b_enc, W_proj, b_proj, emitA, emitB, PA);
    chunk_kernel<<<B_ * NC_, 448, 0, stream>>>(emitA, emitB, lens, trans, dur, Mst, Rst, ezS, Zmx);
    cumwrite_kernel<<<B_ * C_ * NTILE, 64, 0, stream>>>(emitA, emitB, PA, cum);
    chain_kernel<<<16, 320, 0, stream>>>(Mst, ezS, Zmx, Rst, startv, Uv, Xv, Zu, Zx);
    meet_kernel<<<1, 512, 0, stream>>>(Uv, Xv, Zu, Zx, partition);
}